// Round 8
// baseline (474.707 us; speedup 1.0000x reference)
//
#include <hip/hip_runtime.h>
#include <hip/hip_bf16.h>

// NeXtVLAD forward. Round 8: node-count attack (13 -> 7 graph nodes).
// - setup_k absorbs both memsets (wgc direct-write; d_out zeroed by 10 blocks).
// - W2c merged into GEMM1 launch (same kernel, runtime pointer swap).
// - alpha gate computed inside act-GEMM K-loop from the af fragments.
// - fsplit scales+atomicAdds straight into d_out f region (freduce removed);
//   cls_k reads f from d_out, direct-writes.
#define NN 64
#define MM 300
#define CC 768
#define EE 1536          // LAMB*C
#define GG 8
#define KK 64
#define FF 512           // G*K
#define GS 192           // LAMB*C/G
#define PP 2400          // M*G
#define DESC 12288       // K*GS
#define NMROWS 19200     // N*M
#define NB 512
#define NCLS 701
#define OUTSZ (NN*NCLS + NN*NB)   // 77632 floats in d_out

typedef _Float16 v8h __attribute__((ext_vector_type(8)));
typedef _Float16 v4h __attribute__((ext_vector_type(4)));
typedef float    v4f __attribute__((ext_vector_type(4)));

#define GLOAD_LDS16(g, s) \
    __builtin_amdgcn_global_load_lds( \
        (const __attribute__((address_space(1))) void*)(g), \
        (__attribute__((address_space(3))) void*)(s), 16, 0, 0)

// ---------------------------------------------------------------------------
// setup_k: fused preprocessing, branch on blockIdx ranges.
//  [0,14400)        pack features[:,1:] -> xf16
//  [14400,15552)    pack fc0_w -> w1f16
//  [15552,16320)    pack fcgk_w -> w2f16
//  [16320,16608)    transpose fc0_w -> w1t16 (768x1536 fp16)
//  [16608,17128)    composed biases biasc[520]
//  [17128,17140)    Wgc[g,c] = fcg_w@fc0_w (direct write, 12 blocks)
//  [17140,17150)    zero d_out (cls + f regions; fsplit atomics need f=0)
// ---------------------------------------------------------------------------
__global__ __launch_bounds__(256)
void setup_k(const float* __restrict__ features, const float* __restrict__ fc0_w,
             const float* __restrict__ fcgk_w, const float* __restrict__ fcg_w,
             const float* __restrict__ fc0_b, const float* __restrict__ fcgk_b,
             const float* __restrict__ fcg_b,
             _Float16* __restrict__ xf16, _Float16* __restrict__ w1f16,
             _Float16* __restrict__ w2f16, _Float16* __restrict__ w1t16,
             float* __restrict__ biasc, float* __restrict__ wgc,
             float* __restrict__ dout)
{
    __shared__ __align__(16) char sm[16640];
    const int bid = blockIdx.x, tid = threadIdx.x;

    if (bid < 14400) {                       // pack_x
        int idx = bid * 256 + tid;
        int row = idx / 192;
        int c4  = (idx - row * 192) * 4;
        int n = row / 300, m = row - n * 300;
        float4 v = *(const float4*)(features + ((size_t)(n * 301 + m + 1)) * CC + c4);
        v4h h = { (_Float16)v.x, (_Float16)v.y, (_Float16)v.z, (_Float16)v.w };
        *(v4h*)(xf16 + (size_t)row * CC + c4) = h;
        return;
    }
    if (bid < 15552) {                       // pack w1
        int idx = (bid - 14400) * 256 + tid;
        float4 v = *(const float4*)(fc0_w + (size_t)idx * 4);
        v4h h = { (_Float16)v.x, (_Float16)v.y, (_Float16)v.z, (_Float16)v.w };
        *(v4h*)(w1f16 + (size_t)idx * 4) = h;
        return;
    }
    if (bid < 16320) {                       // pack w2
        int idx = (bid - 15552) * 256 + tid;
        float4 v = *(const float4*)(fcgk_w + (size_t)idx * 4);
        v4h h = { (_Float16)v.x, (_Float16)v.y, (_Float16)v.z, (_Float16)v.w };
        *(v4h*)(w2f16 + (size_t)idx * 4) = h;
        return;
    }
    if (bid < 16608) {                       // transpose w1 -> w1t16
        float (*T)[65] = (float(*)[65])sm;
        int b = bid - 16320;
        const int c0 = (b % 12) * 64, e0 = (b / 12) * 64;
        const int tc = tid & 63, te = tid >> 6;
        #pragma unroll
        for (int r = 0; r < 16; ++r) {
            int el = te * 16 + r;
            T[el][tc] = fc0_w[(size_t)(e0 + el) * CC + c0 + tc];
        }
        __syncthreads();
        #pragma unroll
        for (int r = 0; r < 16; ++r) {
            int cl = te * 16 + r;
            w1t16[(size_t)(c0 + cl) * EE + e0 + tc] = (_Float16)T[tc][cl];
        }
        return;
    }
    if (bid < 17128) {                       // composed biases
        float* red = (float*)sm;
        int f = bid - 16608;
        const float* row = (f < FF) ? (fcgk_w + (size_t)f * EE)
                                    : (fcg_w + (size_t)(f - FF) * EE);
        float s = 0.f;
        for (int e = tid; e < EE; e += 256) s += row[e] * fc0_b[e];
        red[tid] = s;
        __syncthreads();
        for (int o = 128; o; o >>= 1) {
            if (tid < o) red[tid] += red[tid + o];
            __syncthreads();
        }
        if (tid == 0)
            biasc[f] = red[0] + ((f < FF) ? fcgk_b[f] : fcg_b[f - FF]);
        return;
    }
    if (bid < 17140) {                       // Wgc direct, 12 blocks
        float (*red)[GG][64] = (float(*)[GG][64])sm;
        int b = bid - 17128;                 // 0..11
        const int c = b * 64 + (tid & 63);
        const int q = tid >> 6;
        float acc[GG] = {};
        for (int e = q * 384; e < q * 384 + 384; ++e) {
            float w1v = fc0_w[(size_t)e * CC + c];
            #pragma unroll
            for (int g = 0; g < GG; ++g) acc[g] = fmaf(fcg_w[g * EE + e], w1v, acc[g]);
        }
        #pragma unroll
        for (int g = 0; g < GG; ++g) red[q][g][tid & 63] = acc[g];
        __syncthreads();
        if (tid < 64) {
            #pragma unroll
            for (int g = 0; g < GG; ++g)
                wgc[g * CC + c] = red[0][g][tid] + red[1][g][tid]
                                + red[2][g][tid] + red[3][g][tid];
        }
        return;
    }
    {                                        // zero d_out, 10 blocks
        int b = bid - 17140;
        for (int idx = b * 256 + tid; idx < OUTSZ; idx += 10 * 256)
            dout[idx] = 0.f;
        return;
    }
}

// ---------------------------------------------------------------------------
// MFMA fp16 GEMM (1D grid, bx=bid%gx, by=bid/gx), 128x128 tile, BK=32,
// XOR-swizzled LDS, 4 waves, 4x4 16x16x32 MFMAs per wave.
// DUAL range: bid>=nblk1 switches to (A2,B2,C2,Ndim2,Kdim2,gx2), no bias.
// SOFTGATE: gate dot computed in the K-loop from af fragments against
// wgc[g,:] (g = wave's 64-col group); epilogue (v+bias)*bn -> softmax over
// the wave's 64-col group * sigmoid(gate) -> fp16 out.
// ---------------------------------------------------------------------------
template<bool OUTF16, bool BN0, bool SOFTGATE>
__global__ __launch_bounds__(256)
void hgemm_nt(const _Float16* __restrict__ A, const _Float16* __restrict__ B,
              const float* __restrict__ bias,
              const float* __restrict__ bn_g, const float* __restrict__ bn_b,
              const float* __restrict__ wgc, const float* __restrict__ gbias,
              void* __restrict__ Cout, int Ndim, int Kdim, int gx,
              int nblk1,
              const _Float16* __restrict__ A2, const _Float16* __restrict__ B2,
              void* __restrict__ C2, int Ndim2, int Kdim2, int gx2)
{
    __shared__ __align__(16) _Float16 As[128 * 32];
    __shared__ __align__(16) _Float16 Bs[128 * 32];
    __shared__ float gsm[4][64];

    const int tid  = threadIdx.x;
    int bid = blockIdx.x;
    const _Float16* Ap = A; const _Float16* Bp = B; void* Cp = Cout;
    const float* bp = bias;
    int Nd = Ndim, Kd = Kdim, g = gx;
    if (bid >= nblk1) {          // second range (W2c) — same code, other args
        bid -= nblk1;
        Ap = A2; Bp = B2; Cp = C2; Nd = Ndim2; Kd = Kdim2; g = gx2;
        bp = nullptr;
    }

    const int wave = tid >> 6, lane = tid & 63;
    const int bx = bid % g, by = bid / g;
    const int wr = wave >> 1, wc = wave & 1;
    const int row0 = by * 128, col0 = bx * 128;

    const int r0 = tid >> 2, cs = tid & 3;
    const int cc = cs ^ ((r0 >> 1) & 3);
    const _Float16* ga0 = Ap + (size_t)(row0 + r0) * Kd + cc * 8;
    const _Float16* ga1 = Ap + (size_t)(row0 + r0 + 64) * Kd + cc * 8;
    const _Float16* gb0 = Bp + (size_t)(col0 + r0) * Kd + cc * 8;
    const _Float16* gb1 = Bp + (size_t)(col0 + r0 + 64) * Kd + cc * 8;
    _Float16* sa0 = As + wave * 512;
    _Float16* sa1 = As + 2048 + wave * 512;
    _Float16* sb0 = Bs + wave * 512;
    _Float16* sb1 = Bs + 2048 + wave * 512;

    v4f acc[4][4];
    #pragma unroll
    for (int i = 0; i < 4; ++i)
        #pragma unroll
        for (int j = 0; j < 4; ++j)
            acc[i][j] = (v4f){0.f, 0.f, 0.f, 0.f};

    const int fm = lane & 15, fq = lane >> 4;
    const int sw = (fm >> 1) & 3;
    const _Float16* arp = As + (wr * 64 + fm) * 32 + (fq ^ sw) * 8;
    const _Float16* brp = Bs + (wc * 64 + fm) * 32 + (fq ^ sw) * 8;

    const int gidx = SOFTGATE ? ((col0 >> 6) + wc) : 0;
    const float* wg = SOFTGATE ? (wgc + (size_t)gidx * CC) : nullptr;
    float gacc[4] = {0.f, 0.f, 0.f, 0.f};

    for (int kt = 0; kt < Kd; kt += 32) {
        GLOAD_LDS16(ga0 + kt, sa0);
        GLOAD_LDS16(ga1 + kt, sa1);
        GLOAD_LDS16(gb0 + kt, sb0);
        GLOAD_LDS16(gb1 + kt, sb1);
        __syncthreads();

        v8h af[4], bf[4];
        #pragma unroll
        for (int i = 0; i < 4; ++i) af[i] = *(const v8h*)(arp + i * 16 * 32);
        #pragma unroll
        for (int j = 0; j < 4; ++j) bf[j] = *(const v8h*)(brp + j * 16 * 32);

        if (SOFTGATE) {
            // af[i][j] = A[row0 + wr*64 + i*16 + fm][kt + fq*8 + j]
            float4 wv0 = *(const float4*)(wg + kt + fq * 8);
            float4 wv1 = *(const float4*)(wg + kt + fq * 8 + 4);
            float w8[8] = {wv0.x, wv0.y, wv0.z, wv0.w, wv1.x, wv1.y, wv1.z, wv1.w};
            #pragma unroll
            for (int i = 0; i < 4; ++i)
                #pragma unroll
                for (int j = 0; j < 8; ++j)
                    gacc[i] = fmaf((float)af[i][j], w8[j], gacc[i]);
        }

        #pragma unroll
        for (int i = 0; i < 4; ++i)
            #pragma unroll
            for (int j = 0; j < 4; ++j)
                acc[i][j] = __builtin_amdgcn_mfma_f32_16x16x32_f16(
                    af[i], bf[j], acc[i][j], 0, 0, 0);
        __syncthreads();
    }

    float bj[4];
    #pragma unroll
    for (int j = 0; j < 4; ++j)
        bj[j] = bp ? bp[col0 + wc * 64 + j * 16 + fm] : 0.f;

    if (SOFTGATE) {
        // finish gate dots: sum over fq groups (lanes fm, fm+16, fm+32, fm+48)
        const float gb = gbias[gidx];
        #pragma unroll
        for (int i = 0; i < 4; ++i) {
            float s = gacc[i];
            s += __shfl_xor(s, 16);
            s += __shfl_xor(s, 32);
            gsm[wave][i * 16 + fm] = 1.f / (1.f + __expf(-(s + gb)));
        }
        // same-wave LDS write->read; compiler inserts the lgkmcnt wait
        #pragma unroll
        for (int i = 0; i < 4; ++i) {
            #pragma unroll
            for (int r = 0; r < 4; ++r) {
                int lrow = i * 16 + fq * 4 + r;
                int grow = row0 + wr * 64 + lrow;
                int n = grow / 300, mm = grow - n * 300;
                float gsc = bn_g[mm], bb = bn_b[mm];
                float v[4];
                #pragma unroll
                for (int j = 0; j < 4; ++j)
                    v[j] = (acc[i][j][r] + bj[j]) * gsc + bb;
                float mx = fmaxf(fmaxf(v[0], v[1]), fmaxf(v[2], v[3]));
                #pragma unroll
                for (int w = 1; w < 16; w <<= 1) mx = fmaxf(mx, __shfl_xor(mx, w));
                float e[4], s = 0.f;
                #pragma unroll
                for (int j = 0; j < 4; ++j) { e[j] = __expf(v[j] - mx); s += e[j]; }
                #pragma unroll
                for (int w = 1; w < 16; w <<= 1) s += __shfl_xor(s, w);
                float gate = gsm[wave][lrow];
                float inv = gate / s;
                _Float16* cp = (_Float16*)Cp + (size_t)grow * Nd + col0 + wc * 64;
                #pragma unroll
                for (int j = 0; j < 4; ++j) cp[j * 16 + fm] = (_Float16)(e[j] * inv);
            }
        }
        return;
    }

    #pragma unroll
    for (int i = 0; i < 4; ++i) {
        #pragma unroll
        for (int r = 0; r < 4; ++r) {
            int grow = row0 + wr * 64 + i * 16 + fq * 4 + r;
            float gsc = 1.f, bb = 0.f;
            if (BN0) { int m = grow % 300; gsc = bn_g[m]; bb = bn_b[m]; }
            #pragma unroll
            for (int j = 0; j < 4; ++j) {
                int gcol = col0 + wc * 64 + j * 16 + fm;
                float v = acc[i][j][r] + bj[j];
                if (BN0) v = v * gsc + bb;
                if (OUTF16)
                    ((_Float16*)Cp)[(size_t)grow * Nd + gcol] = (_Float16)v;
                else
                    ((float*)Cp)[(size_t)grow * Nd + gcol] = v;
            }
        }
    }
}

// ---------------------------------------------------------------------------
// vladact_k: fused vlad split-P partials [0,1536) + asum partials [1536,2048).
// ---------------------------------------------------------------------------
__global__ __launch_bounds__(256)
void vladact_k(const _Float16* __restrict__ act, const _Float16* __restrict__ xdot,
               float* __restrict__ part, float* __restrict__ apart)
{
    __shared__ __align__(16) char sm[8192];
    const int tid = threadIdx.x, bid = blockIdx.x;

    if (bid >= 1536) {                       // ---- asum tail ----
        float (*red)[64] = (float(*)[64])sm;
        int b = bid - 1536;
        const int ps = b & 7, n = b >> 3;
        const int k = tid & 63, q = tid >> 6;
        const _Float16* base = act + ((size_t)n * PP + ps * 300 + q * 75) * 64 + k;
        float s = 0.f;
        for (int p = 0; p < 75; ++p) s += (float)base[(size_t)p * 64];
        red[q][k] = s;
        __syncthreads();
        if (tid < 64)
            apart[((size_t)ps * NN + n) * 64 + tid] =
                red[0][tid] + red[1][tid] + red[2][tid] + red[3][tid];
        return;
    }

    float (*As)[64] = (float(*)[64])sm;              // 16x64
    float (*Xs)[64] = (float(*)[64])(sm + 4096);
    const int dt = bid % 3, n = (bid / 3) & 63, ps = bid / 192;
    const int d0 = dt * 64;
    const int p0 = ps * 300, pend = p0 + 300;
    const int tx = tid & 15, ty = tid >> 4;
    const int kb = tx * 4, db = ty * 4;
    const _Float16* actn = act + (size_t)n * PP * 64;
    const _Float16* xn   = xdot + (size_t)n * MM * EE;
    float acc[4][4] = {};

    const int lpp = tid >> 4, lk4 = (tid & 15) << 2;
    for (int pc = p0; pc < pend; pc += 16) {
        int p = pc + lpp;
        float a0 = 0.f, a1 = 0.f, a2 = 0.f, a3 = 0.f;
        float x0 = 0.f, x1 = 0.f, x2 = 0.f, x3 = 0.f;
        if (p < pend) {
            v4h avh = *(const v4h*)(actn + (size_t)p * 64 + lk4);
            a0 = (float)avh[0]; a1 = (float)avh[1]; a2 = (float)avh[2]; a3 = (float)avh[3];
            v4h xv = *(const v4h*)(xn + (size_t)(p >> 3) * EE + (p & 7) * GS + d0 + lk4);
            x0 = (float)xv[0]; x1 = (float)xv[1]; x2 = (float)xv[2]; x3 = (float)xv[3];
        }
        As[lpp][lk4 + 0] = a0; As[lpp][lk4 + 1] = a1;
        As[lpp][lk4 + 2] = a2; As[lpp][lk4 + 3] = a3;
        Xs[lpp][lk4 + 0] = x0; Xs[lpp][lk4 + 1] = x1;
        Xs[lpp][lk4 + 2] = x2; Xs[lpp][lk4 + 3] = x3;
        __syncthreads();
        #pragma unroll
        for (int q = 0; q < 16; ++q) {
            float4 a4 = *(const float4*)&As[q][kb];
            float4 x4 = *(const float4*)&Xs[q][db];
            float aa[4] = {a4.x, a4.y, a4.z, a4.w};
            float xx[4] = {x4.x, x4.y, x4.z, x4.w};
            #pragma unroll
            for (int i = 0; i < 4; ++i)
                #pragma unroll
                for (int j = 0; j < 4; ++j)
                    acc[i][j] = fmaf(xx[i], aa[j], acc[i][j]);
        }
        __syncthreads();
    }

    float* pp = part + ((size_t)ps * NN + n) * DESC;
    #pragma unroll
    for (int i = 0; i < 4; ++i) {
        int dd = d0 + db + i;
        float4 o = {acc[i][0], acc[i][1], acc[i][2], acc[i][3]};
        *(float4*)(pp + (size_t)dd * 64 + kb) = o;
    }
}

// ---------------------------------------------------------------------------
// vladnorm_k: vlad[n,d,k] = ((sum_ps part - a*cw2) * L1scale * bn1g + bn1b)
// ---------------------------------------------------------------------------
__global__ __launch_bounds__(256)
void vladnorm_k(const float* __restrict__ part, const float* __restrict__ apart,
                const float* __restrict__ cw2, const float* __restrict__ bn1g,
                const float* __restrict__ bn1b, float* __restrict__ vlad)
{
    const int n = blockIdx.x >> 2, kq = blockIdx.x & 3;
    const int tk = threadIdx.x & 15, td = threadIdx.x >> 4;
    const int k = kq * 16 + tk;

    float a = 0.f;
    #pragma unroll
    for (int ps = 0; ps < 8; ++ps) a += apart[((size_t)ps * NN + n) * 64 + k];

    float vloc[12];
    float sabs = 0.f;
    #pragma unroll
    for (int i = 0; i < 12; ++i) {
        int d = td * 12 + i;
        float s = 0.f;
        #pragma unroll
        for (int ps = 0; ps < 8; ++ps)
            s += part[((size_t)ps * NN + n) * DESC + (size_t)d * 64 + k];
        float v = s - a * cw2[d * 64 + k];
        vloc[i] = v;
        sabs += fabsf(v);
    }

    __shared__ float red[16][16];
    __shared__ float inv[16];
    red[td][tk] = sabs;
    __syncthreads();
    if (td == 0) {
        float t = 0.f;
        #pragma unroll
        for (int q = 0; q < 16; ++q) t += red[q][tk];
        inv[tk] = 1.f / fmaxf(t, 1e-12f);
    }
    __syncthreads();
    const float g = bn1g[0], b = bn1b[0];
    const float sc = inv[tk] * g;
    #pragma unroll
    for (int i = 0; i < 12; ++i) {
        int d = td * 12 + i;
        vlad[(size_t)n * DESC + (size_t)d * 64 + k] = vloc[i] * sc + b;
    }
}

// ---------------------------------------------------------------------------
// fsplit_k: partial = sum_{k chunk} vlad[n,k]*W[b,k]; epilogue scales by
// bng[b] and atomicAdds into f (d_out, pre-zeroed). ks==0 adds the affine
// constant bias[b]*bng[b]+bnb[b]. Replaces fsplit+freduce.
// ---------------------------------------------------------------------------
__global__ __launch_bounds__(256)
void fsplit_k(const float* __restrict__ vlad, const float* __restrict__ W,
              const float* __restrict__ bias, const float* __restrict__ bng,
              const float* __restrict__ bnb, float* __restrict__ f)
{
    const int bcol0 = (blockIdx.x & 7) * 64;
    const int ks = blockIdx.x >> 3;
    const int kc0 = ks * 256;
    __shared__ float Vs[32][68];
    __shared__ float Ws[32][68];
    const int tid = threadIdx.x, tx = tid & 15, ty = tid >> 4;
    float acc[4][4] = {};

    for (int kc = kc0; kc < kc0 + 256; kc += 32) {
        #pragma unroll
        for (int it = 0; it < 2; ++it) {
            int sl = tid + it * 256;
            int rr = sl >> 3, k4 = (sl & 7) << 2;
            float4 v = *(const float4*)(vlad + (size_t)rr * DESC + kc + k4);
            Vs[k4+0][rr] = v.x; Vs[k4+1][rr] = v.y; Vs[k4+2][rr] = v.z; Vs[k4+3][rr] = v.w;
            float4 w = *(const float4*)(W + (size_t)(bcol0 + rr) * DESC + kc + k4);
            Ws[k4+0][rr] = w.x; Ws[k4+1][rr] = w.y; Ws[k4+2][rr] = w.z; Ws[k4+3][rr] = w.w;
        }
        __syncthreads();
        #pragma unroll
        for (int q = 0; q < 32; ++q) {
            float4 wv = *(const float4*)&Ws[q][tx*4];
            float4 vv = *(const float4*)&Vs[q][ty*4];
            float wa[4] = {wv.x, wv.y, wv.z, wv.w};
            float va[4] = {vv.x, vv.y, vv.z, vv.w};
            #pragma unroll
            for (int i = 0; i < 4; ++i)
                #pragma unroll
                for (int j = 0; j < 4; ++j)
                    acc[i][j] = fmaf(va[i], wa[j], acc[i][j]);
        }
        __syncthreads();
    }

    float gj[4], cj[4];
    #pragma unroll
    for (int j = 0; j < 4; ++j) {
        int b = bcol0 + tx * 4 + j;
        gj[j] = bng[b];
        cj[j] = (ks == 0) ? (bias[b] * bng[b] + bnb[b]) : 0.f;
    }
    #pragma unroll
    for (int i = 0; i < 4; ++i) {
        int n = ty * 4 + i;
        #pragma unroll
        for (int j = 0; j < 4; ++j) {
            int b = bcol0 + tx * 4 + j;
            atomicAdd(&f[(size_t)n * NB + b], acc[i][j] * gj[j] + cj[j]);
        }
    }
}

// ---------------------------------------------------------------------------
// cls_k: cls[n,c] = dot(f[n,:512], cls_w[c,:512]) + cls_b[c]; 11 blocks,
// full-K, direct write (no atomics, no memset dependency for cls region).
// ---------------------------------------------------------------------------
__global__ __launch_bounds__(256)
void cls_k(const float* __restrict__ f, const float* __restrict__ W,
           const float* __restrict__ bias, float* __restrict__ out)
{
    const int c0 = blockIdx.x * 64;
    __shared__ float Fs[32][68];
    __shared__ float Ws[32][68];
    const int tid = threadIdx.x, tx = tid & 15, ty = tid >> 4;
    float acc[4][4] = {};

    for (int kc = 0; kc < NB; kc += 32) {
        #pragma unroll
        for (int it = 0; it < 2; ++it) {
            int sl = tid + it * 256;
            int rr = sl >> 3, k4 = (sl & 7) << 2;
            float4 v = *(const float4*)(f + (size_t)rr * NB + kc + k4);
            Fs[k4+0][rr] = v.x; Fs[k4+1][rr] = v.y; Fs[k4+2][rr] = v.z; Fs[k4+3][rr] = v.w;
            int c = c0 + rr;
            float4 w = (c < NCLS) ? *(const float4*)(W + (size_t)c * NB + kc + k4)
                                  : make_float4(0.f, 0.f, 0.f, 0.f);
            Ws[k4+0][rr] = w.x; Ws[k4+1][rr] = w.y; Ws[k4+2][rr] = w.z; Ws[k4+3][rr] = w.w;
        }
        __syncthreads();
        #pragma unroll
        for (int q = 0; q < 32; ++q) {
            float4 wv = *(const float4*)&Ws[q][tx*4];
            float4 fv = *(const float4*)&Fs[q][ty*4];
            float wa[4] = {wv.x, wv.y, wv.z, wv.w};
            float fa[4] = {fv.x, fv.y, fv.z, fv.w};
            #pragma unroll
            for (int i = 0; i < 4; ++i)
                #pragma unroll
                for (int j = 0; j < 4; ++j)
                    acc[i][j] = fmaf(fa[i], wa[j], acc[i][j]);
        }
        __syncthreads();
    }
    #pragma unroll
    for (int i = 0; i < 4; ++i) {
        int n = ty * 4 + i;
        #pragma unroll
        for (int j = 0; j < 4; ++j) {
            int c = c0 + tx * 4 + j;
            if (c < NCLS) out[(size_t)n * NCLS + c] = acc[i][j] + bias[c];
        }
    }
}

// ---------------------------------------------------------------------------
extern "C" void kernel_launch(void* const* d_in, const int* in_sizes, int n_in,
                              void* d_out, int out_size, void* d_ws, size_t ws_size,
                              hipStream_t stream)
{
    const float* features = (const float*)d_in[0];
    const float* fc0_w    = (const float*)d_in[1];
    const float* fc0_b    = (const float*)d_in[2];
    const float* fcgk_w   = (const float*)d_in[3];
    const float* fcgk_b   = (const float*)d_in[4];
    const float* fcg_w    = (const float*)d_in[5];
    const float* fcg_b    = (const float*)d_in[6];
    const float* bn0_g    = (const float*)d_in[7];
    const float* bn0_b    = (const float*)d_in[8];
    const float* cw2      = (const float*)d_in[9];
    const float* bn1_g    = (const float*)d_in[10];
    const float* bn1_b    = (const float*)d_in[11];
    const float* cls_fc_w = (const float*)d_in[12];
    const float* cls_fc_b = (const float*)d_in[13];
    const float* cls_bn_g = (const float*)d_in[14];
    const float* cls_bn_b = (const float*)d_in[15];
    const float* cls_w    = (const float*)d_in[16];
    const float* cls_b    = (const float*)d_in[17];

    // Workspace layout (bytes). Total ~143.7 MB.
    char* ws = (char*)d_ws;
    _Float16* xf16   = (_Float16*)(ws + 0);            // 29,491,200
    _Float16* w1f16  = (_Float16*)(ws + 29491200);     //  2,359,296
    _Float16* w2f16  = (_Float16*)(ws + 31850496);     //  1,572,864
    _Float16* w1t16  = (_Float16*)(ws + 33423360);     //  2,359,296
    _Float16* w2cf16 = (_Float16*)(ws + 35782656);     //    786,432
    float*    biasc  = (float*)   (ws + 36569088);     //      4,096
    float*    wgc    = (float*)   (ws + 36573184);     //     24,576
    _Float16* xdot16 = (_Float16*)(ws + 36597760);     // 58,982,400
    _Float16* act16  = (_Float16*)(ws + 95580160);     // 19,660,800
    float*    apart  = (float*)   (ws + 115240960);    //    131,072
    float*    vpart  = (float*)   (ws + 115372032);    // 25,165,824
    float*    vlad   = (float*)   (ws + 140537856);    //  3,145,728 -> 143,683,584

    float* cls_out = (float*)d_out;          // 64*701
    float* f_out   = cls_out + NN * NCLS;    // 64*512 (atomic-accumulated)

    dim3 blk(256);

    // 1. setup: packs + transpose + biasc + Wgc(direct) + zero d_out
    setup_k<<<17150, blk, 0, stream>>>(features, fc0_w, fcgk_w, fcg_w,
                                       fc0_b, fcgk_b, fcg_b,
                                       xf16, w1f16, w2f16, w1t16, biasc, wgc,
                                       (float*)d_out);

    // 2. GEMM1 (x_dot = x@W1^T + b0, 19200x1536 K=768 -> fp16) [0,1800)
    //    + W2c (= W2@W1, 512x768 K=1536 -> fp16)               [1800,1824)
    hgemm_nt<true, false, false><<<1824, blk, 0, stream>>>(
        xf16, w1f16, fc0_b, nullptr, nullptr, nullptr, nullptr,
        xdot16, EE, CC, 12,
        1800, w2f16, w1t16, w2cf16, CC, EE, 6);

    // 3. act = softmax((x @ W2c^T + biasc)*bn0) * sigmoid(x@Wgc^T + bgc)
    //    (19200x512, K=768, gate computed in-loop) -> fp16
    hgemm_nt<true, true, true><<<600, blk, 0, stream>>>(
        xf16, w2cf16, biasc, bn0_g, bn0_b, wgc, biasc + FF,
        act16, FF, CC, 4,
        600, nullptr, nullptr, nullptr, 0, 0, 1);

    // 4. vlad partials (split-P x8) + asum partials
    vladact_k<<<2048, blk, 0, stream>>>(act16, xdot16, vpart, apart);

    // 5. reduce + (-a*cw2) + L1-norm + bn1 -> vlad (fp32)
    vladnorm_k<<<256, blk, 0, stream>>>(vpart, apart, cw2, bn1_g, bn1_b, vlad);

    // 6. f = (vlad @ cls_fc_w^T + bias)*bng + bnb, scaled-atomic into d_out
    fsplit_k<<<384, blk, 0, stream>>>(vlad, cls_fc_w, cls_fc_b,
                                      cls_bn_g, cls_bn_b, f_out);

    // 7. cls = f @ cls_w^T + cls_b (direct write)
    cls_k<<<11, blk, 0, stream>>>(f_out, cls_w, cls_b, cls_out);
}

// Round 9
// 442.813 us; speedup vs baseline: 1.0720x; 1.0720x over previous
//
#include <hip/hip_runtime.h>
#include <hip/hip_bf16.h>

// NeXtVLAD forward. Round 9: r7 structure (known-good 448.6 us, absmax 2.44e-4)
// with ONE change: hgemm_nt BK 32 -> 64 (halves barrier drains per K-loop).
// r8's merges reverted (W2c tail + in-loop gate + fsplit atomics regressed).
#define NN 64
#define MM 300
#define CC 768
#define EE 1536          // LAMB*C
#define GG 8
#define KK 64
#define FF 512           // G*K
#define GS 192           // LAMB*C/G
#define PP 2400          // M*G
#define DESC 12288       // K*GS
#define NMROWS 19200     // N*M
#define NB 512
#define NCLS 701

typedef _Float16 v8h __attribute__((ext_vector_type(8)));
typedef _Float16 v4h __attribute__((ext_vector_type(4)));
typedef float    v4f __attribute__((ext_vector_type(4)));

#define GLOAD_LDS16(g, s) \
    __builtin_amdgcn_global_load_lds( \
        (const __attribute__((address_space(1))) void*)(g), \
        (__attribute__((address_space(3))) void*)(s), 16, 0, 0)

// ---------------------------------------------------------------------------
// setup_k: fused preprocessing, branch on blockIdx ranges (r7 version).
// ---------------------------------------------------------------------------
__global__ __launch_bounds__(256)
void setup_k(const float* __restrict__ features, const float* __restrict__ fc0_w,
             const float* __restrict__ fcgk_w, const float* __restrict__ fcg_w,
             const float* __restrict__ fc0_b, const float* __restrict__ fcgk_b,
             const float* __restrict__ fcg_b,
             _Float16* __restrict__ xf16, _Float16* __restrict__ w1f16,
             _Float16* __restrict__ w2f16, _Float16* __restrict__ w1t16,
             float* __restrict__ biasc, float* __restrict__ wgc)
{
    __shared__ __align__(16) char sm[16640];
    const int bid = blockIdx.x, tid = threadIdx.x;

    if (bid < 14400) {                       // pack_x
        int idx = bid * 256 + tid;
        int row = idx / 192;
        int c4  = (idx - row * 192) * 4;
        int n = row / 300, m = row - n * 300;
        float4 v = *(const float4*)(features + ((size_t)(n * 301 + m + 1)) * CC + c4);
        v4h h = { (_Float16)v.x, (_Float16)v.y, (_Float16)v.z, (_Float16)v.w };
        *(v4h*)(xf16 + (size_t)row * CC + c4) = h;
        return;
    }
    if (bid < 15552) {                       // pack w1
        int idx = (bid - 14400) * 256 + tid;
        float4 v = *(const float4*)(fc0_w + (size_t)idx * 4);
        v4h h = { (_Float16)v.x, (_Float16)v.y, (_Float16)v.z, (_Float16)v.w };
        *(v4h*)(w1f16 + (size_t)idx * 4) = h;
        return;
    }
    if (bid < 16320) {                       // pack w2
        int idx = (bid - 15552) * 256 + tid;
        float4 v = *(const float4*)(fcgk_w + (size_t)idx * 4);
        v4h h = { (_Float16)v.x, (_Float16)v.y, (_Float16)v.z, (_Float16)v.w };
        *(v4h*)(w2f16 + (size_t)idx * 4) = h;
        return;
    }
    if (bid < 16608) {                       // transpose w1 -> w1t16
        float (*T)[65] = (float(*)[65])sm;
        int b = bid - 16320;
        const int c0 = (b % 12) * 64, e0 = (b / 12) * 64;
        const int tc = tid & 63, te = tid >> 6;
        #pragma unroll
        for (int r = 0; r < 16; ++r) {
            int el = te * 16 + r;
            T[el][tc] = fc0_w[(size_t)(e0 + el) * CC + c0 + tc];
        }
        __syncthreads();
        #pragma unroll
        for (int r = 0; r < 16; ++r) {
            int cl = te * 16 + r;
            w1t16[(size_t)(c0 + cl) * EE + e0 + tc] = (_Float16)T[tc][cl];
        }
        return;
    }
    if (bid < 17128) {                       // composed biases
        float* red = (float*)sm;
        int f = bid - 16608;
        const float* row = (f < FF) ? (fcgk_w + (size_t)f * EE)
                                    : (fcg_w + (size_t)(f - FF) * EE);
        float s = 0.f;
        for (int e = tid; e < EE; e += 256) s += row[e] * fc0_b[e];
        red[tid] = s;
        __syncthreads();
        for (int o = 128; o; o >>= 1) {
            if (tid < o) red[tid] += red[tid + o];
            __syncthreads();
        }
        if (tid == 0)
            biasc[f] = red[0] + ((f < FF) ? fcgk_b[f] : fcg_b[f - FF]);
        return;
    }
    {                                        // Wgc, 8-way e-split + atomics
        float (*red)[GG][64] = (float(*)[GG][64])sm;
        int b = bid - 17128;                 // 0..95
        const int c = (b % 12) * 64 + (tid & 63);
        const int es = b / 12, q = tid >> 6;
        float acc[GG] = {};
        for (int e = es * 192 + q * 48; e < es * 192 + q * 48 + 48; ++e) {
            float w1v = fc0_w[(size_t)e * CC + c];
            #pragma unroll
            for (int g = 0; g < GG; ++g) acc[g] = fmaf(fcg_w[g * EE + e], w1v, acc[g]);
        }
        #pragma unroll
        for (int g = 0; g < GG; ++g) red[q][g][tid & 63] = acc[g];
        __syncthreads();
        if (tid < 64) {
            #pragma unroll
            for (int g = 0; g < GG; ++g) {
                float v = red[0][g][tid] + red[1][g][tid] + red[2][g][tid] + red[3][g][tid];
                atomicAdd(&wgc[g * CC + c], v);
            }
        }
        return;
    }
}

// ---------------------------------------------------------------------------
// MFMA fp16 GEMM, BK=64 (1D grid, bx=bid%gx, by=bid/gx):
//   C[i,j] = sum_k A[i,k]*B[j,k] (+bias[j]); 128x128 tile, 4 waves,
//   4x4 16x16x32 MFMAs per wave per 32-k half, two halves per iteration.
// LDS: 128 rows x 64 halves per matrix (16 KB each). Chunk XOR swizzle:
//   chunk c of row r stored at slot c ^ (r&7); fragment read slot
//   (h*4+fq) ^ (fm&7) -> <=2-way bank alias.
// SOFTGATE: epilogue (v+bias)*bn -> softmax over wave's 64-col group * gate.
// ---------------------------------------------------------------------------
template<bool OUTF16, bool BN0, bool SOFTGATE, bool BIAS>
__global__ __launch_bounds__(256)
void hgemm_nt(const _Float16* __restrict__ A, const _Float16* __restrict__ B,
              const float* __restrict__ bias,
              const float* __restrict__ bn_g, const float* __restrict__ bn_b,
              const float* __restrict__ sig,
              void* __restrict__ Cout, int Ndim, int Kdim, int gx)
{
    __shared__ __align__(16) _Float16 As[128 * 64];   // 16 KB
    __shared__ __align__(16) _Float16 Bs[128 * 64];   // 16 KB

    const int tid  = threadIdx.x;
    const int bid  = blockIdx.x;
    const int wave = tid >> 6, lane = tid & 63;
    const int bx = bid % gx, by = bid / gx;
    const int wr = wave >> 1, wc = wave & 1;
    const int row0 = by * 128, col0 = bx * 128;

    // staging: 1024 x 16B chunks per matrix, 4 insts x 256 lanes each.
    // inst t, thread tid -> slot t*256+tid -> row t*32 + (tid>>3),
    // stored chunk cs = tid&7, source chunk cc = cs ^ ((tid>>3)&7).
    const int r0 = tid >> 3, cs = tid & 7;
    const int cc = cs ^ (r0 & 7);
    const _Float16* ga[4];
    const _Float16* gb[4];
    #pragma unroll
    for (int t = 0; t < 4; ++t) {
        ga[t] = A + (size_t)(row0 + t * 32 + r0) * Kdim + cc * 8;
        gb[t] = B + (size_t)(col0 + t * 32 + r0) * Kdim + cc * 8;
    }
    _Float16* sa[4];
    _Float16* sb[4];
    #pragma unroll
    for (int t = 0; t < 4; ++t) {
        sa[t] = As + t * 2048 + wave * 512;
        sb[t] = Bs + t * 2048 + wave * 512;
    }

    v4f acc[4][4];
    #pragma unroll
    for (int i = 0; i < 4; ++i)
        #pragma unroll
        for (int j = 0; j < 4; ++j)
            acc[i][j] = (v4f){0.f, 0.f, 0.f, 0.f};

    const int fm = lane & 15, fq = lane >> 4;
    const int sw = fm & 7;                       // row&7 key (rows step 16)
    const _Float16* arow = As + (wr * 64 + fm) * 64;
    const _Float16* brow = Bs + (wc * 64 + fm) * 64;

    for (int kt = 0; kt < Kdim; kt += 64) {
        #pragma unroll
        for (int t = 0; t < 4; ++t) {
            GLOAD_LDS16(ga[t] + kt, sa[t]);
            GLOAD_LDS16(gb[t] + kt, sb[t]);
        }
        __syncthreads();

        #pragma unroll
        for (int h = 0; h < 2; ++h) {
            const int slot = ((h << 2) + fq) ^ sw;
            v8h af[4], bf[4];
            #pragma unroll
            for (int i = 0; i < 4; ++i)
                af[i] = *(const v8h*)(arow + i * 16 * 64 + slot * 8);
            #pragma unroll
            for (int j = 0; j < 4; ++j)
                bf[j] = *(const v8h*)(brow + j * 16 * 64 + slot * 8);
            #pragma unroll
            for (int i = 0; i < 4; ++i)
                #pragma unroll
                for (int j = 0; j < 4; ++j)
                    acc[i][j] = __builtin_amdgcn_mfma_f32_16x16x32_f16(
                        af[i], bf[j], acc[i][j], 0, 0, 0);
        }
        __syncthreads();
    }

    float bj[4];
    #pragma unroll
    for (int j = 0; j < 4; ++j)
        bj[j] = BIAS ? bias[col0 + wc * 64 + j * 16 + fm] : 0.f;

    if (SOFTGATE) {
        const int gidx = (col0 >> 6) + wc;
        #pragma unroll
        for (int i = 0; i < 4; ++i) {
            #pragma unroll
            for (int r = 0; r < 4; ++r) {
                int grow = row0 + wr * 64 + i * 16 + fq * 4 + r;
                int n = grow / 300, mm = grow - n * 300;
                float g = bn_g[mm], bb = bn_b[mm];
                float v[4];
                #pragma unroll
                for (int j = 0; j < 4; ++j)
                    v[j] = (acc[i][j][r] + bj[j]) * g + bb;
                float mx = fmaxf(fmaxf(v[0], v[1]), fmaxf(v[2], v[3]));
                #pragma unroll
                for (int w = 1; w < 16; w <<= 1) mx = fmaxf(mx, __shfl_xor(mx, w));
                float e[4], s = 0.f;
                #pragma unroll
                for (int j = 0; j < 4; ++j) { e[j] = __expf(v[j] - mx); s += e[j]; }
                #pragma unroll
                for (int w = 1; w < 16; w <<= 1) s += __shfl_xor(s, w);
                float gate = sig[(size_t)grow * GG + gidx];
                float inv = gate / s;
                _Float16* cp = (_Float16*)Cout + (size_t)grow * Ndim + col0 + wc * 64;
                #pragma unroll
                for (int j = 0; j < 4; ++j) cp[j * 16 + fm] = (_Float16)(e[j] * inv);
            }
        }
        return;
    }

    #pragma unroll
    for (int i = 0; i < 4; ++i) {
        #pragma unroll
        for (int r = 0; r < 4; ++r) {
            int grow = row0 + wr * 64 + i * 16 + fq * 4 + r;
            float g = 1.f, bb = 0.f;
            if (BN0) { int m = grow % 300; g = bn_g[m]; bb = bn_b[m]; }
            #pragma unroll
            for (int j = 0; j < 4; ++j) {
                int gcol = col0 + wc * 64 + j * 16 + fm;
                float v = acc[i][j][r] + bj[j];
                if (BN0) v = v * g + bb;
                if (OUTF16)
                    ((_Float16*)Cout)[(size_t)grow * Ndim + gcol] = (_Float16)v;
                else
                    ((float*)Cout)[(size_t)grow * Ndim + gcol] = v;
            }
        }
    }
}

// ---------------------------------------------------------------------------
// alpha_g from xf16 with composed Wgc (8x768 fp32 in LDS) + composed bias.
// ---------------------------------------------------------------------------
__global__ __launch_bounds__(256)
void alpha_sig_k(const _Float16* __restrict__ x, const float* __restrict__ wgc,
                 const float* __restrict__ bgc, float* __restrict__ sig)
{
    __shared__ float W[GG * CC];   // 24 KB
    for (int i = threadIdx.x; i < GG * CC; i += 256) W[i] = wgc[i];
    __syncthreads();

    const int wave = threadIdx.x >> 6;
    const int lane = threadIdx.x & 63;

    for (int rr = 0; rr < 4; ++rr) {
        int row = blockIdx.x * 16 + wave * 4 + rr;
        const _Float16* xr = x + (size_t)row * CC;
        float acc[GG] = {};
        for (int c = lane; c < CC; c += 64) {
            float xv = (float)xr[c];
            #pragma unroll
            for (int g = 0; g < GG; ++g) acc[g] = fmaf(xv, W[g * CC + c], acc[g]);
        }
        float myval = 0.f;
        #pragma unroll
        for (int g = 0; g < GG; ++g) {
            float s = acc[g];
            #pragma unroll
            for (int o = 32; o; o >>= 1) s += __shfl_xor(s, o);
            if (lane == g) myval = s + bgc[g];
        }
        if (lane < GG)
            sig[(size_t)row * GG + lane] = 1.f / (1.f + __expf(-myval));
    }
}

// ---------------------------------------------------------------------------
// vladact_k: fused vlad split-P partials [0,1536) + asum partials [1536,2048).
// ---------------------------------------------------------------------------
__global__ __launch_bounds__(256)
void vladact_k(const _Float16* __restrict__ act, const _Float16* __restrict__ xdot,
               float* __restrict__ part, float* __restrict__ apart)
{
    __shared__ __align__(16) char sm[8192];
    const int tid = threadIdx.x, bid = blockIdx.x;

    if (bid >= 1536) {                       // ---- asum tail ----
        float (*red)[64] = (float(*)[64])sm;
        int b = bid - 1536;
        const int ps = b & 7, n = b >> 3;
        const int k = tid & 63, q = tid >> 6;
        const _Float16* base = act + ((size_t)n * PP + ps * 300 + q * 75) * 64 + k;
        float s = 0.f;
        for (int p = 0; p < 75; ++p) s += (float)base[(size_t)p * 64];
        red[q][k] = s;
        __syncthreads();
        if (tid < 64)
            apart[((size_t)ps * NN + n) * 64 + tid] =
                red[0][tid] + red[1][tid] + red[2][tid] + red[3][tid];
        return;
    }

    float (*As)[64] = (float(*)[64])sm;              // 16x64
    float (*Xs)[64] = (float(*)[64])(sm + 4096);
    const int dt = bid % 3, n = (bid / 3) & 63, ps = bid / 192;
    const int d0 = dt * 64;
    const int p0 = ps * 300, pend = p0 + 300;
    const int tx = tid & 15, ty = tid >> 4;
    const int kb = tx * 4, db = ty * 4;
    const _Float16* actn = act + (size_t)n * PP * 64;
    const _Float16* xn   = xdot + (size_t)n * MM * EE;
    float acc[4][4] = {};

    const int lpp = tid >> 4, lk4 = (tid & 15) << 2;
    for (int pc = p0; pc < pend; pc += 16) {
        int p = pc + lpp;
        float a0 = 0.f, a1 = 0.f, a2 = 0.f, a3 = 0.f;
        float x0 = 0.f, x1 = 0.f, x2 = 0.f, x3 = 0.f;
        if (p < pend) {
            v4h avh = *(const v4h*)(actn + (size_t)p * 64 + lk4);
            a0 = (float)avh[0]; a1 = (float)avh[1]; a2 = (float)avh[2]; a3 = (float)avh[3];
            v4h xv = *(const v4h*)(xn + (size_t)(p >> 3) * EE + (p & 7) * GS + d0 + lk4);
            x0 = (float)xv[0]; x1 = (float)xv[1]; x2 = (float)xv[2]; x3 = (float)xv[3];
        }
        As[lpp][lk4 + 0] = a0; As[lpp][lk4 + 1] = a1;
        As[lpp][lk4 + 2] = a2; As[lpp][lk4 + 3] = a3;
        Xs[lpp][lk4 + 0] = x0; Xs[lpp][lk4 + 1] = x1;
        Xs[lpp][lk4 + 2] = x2; Xs[lpp][lk4 + 3] = x3;
        __syncthreads();
        #pragma unroll
        for (int q = 0; q < 16; ++q) {
            float4 a4 = *(const float4*)&As[q][kb];
            float4 x4 = *(const float4*)&Xs[q][db];
            float aa[4] = {a4.x, a4.y, a4.z, a4.w};
            float xx[4] = {x4.x, x4.y, x4.z, x4.w};
            #pragma unroll
            for (int i = 0; i < 4; ++i)
                #pragma unroll
                for (int j = 0; j < 4; ++j)
                    acc[i][j] = fmaf(xx[i], aa[j], acc[i][j]);
        }
        __syncthreads();
    }

    float* pp = part + ((size_t)ps * NN + n) * DESC;
    #pragma unroll
    for (int i = 0; i < 4; ++i) {
        int dd = d0 + db + i;
        float4 o = {acc[i][0], acc[i][1], acc[i][2], acc[i][3]};
        *(float4*)(pp + (size_t)dd * 64 + kb) = o;
    }
}

// ---------------------------------------------------------------------------
// vladnorm_k: vlad[n,d,k] = ((sum_ps part - a*cw2) * L1scale * bn1g + bn1b)
// ---------------------------------------------------------------------------
__global__ __launch_bounds__(256)
void vladnorm_k(const float* __restrict__ part, const float* __restrict__ apart,
                const float* __restrict__ cw2, const float* __restrict__ bn1g,
                const float* __restrict__ bn1b, float* __restrict__ vlad)
{
    const int n = blockIdx.x >> 2, kq = blockIdx.x & 3;
    const int tk = threadIdx.x & 15, td = threadIdx.x >> 4;
    const int k = kq * 16 + tk;

    float a = 0.f;
    #pragma unroll
    for (int ps = 0; ps < 8; ++ps) a += apart[((size_t)ps * NN + n) * 64 + k];

    float vloc[12];
    float sabs = 0.f;
    #pragma unroll
    for (int i = 0; i < 12; ++i) {
        int d = td * 12 + i;
        float s = 0.f;
        #pragma unroll
        for (int ps = 0; ps < 8; ++ps)
            s += part[((size_t)ps * NN + n) * DESC + (size_t)d * 64 + k];
        float v = s - a * cw2[d * 64 + k];
        vloc[i] = v;
        sabs += fabsf(v);
    }

    __shared__ float red[16][16];
    __shared__ float inv[16];
    red[td][tk] = sabs;
    __syncthreads();
    if (td == 0) {
        float t = 0.f;
        #pragma unroll
        for (int q = 0; q < 16; ++q) t += red[q][tk];
        inv[tk] = 1.f / fmaxf(t, 1e-12f);
    }
    __syncthreads();
    const float g = bn1g[0], b = bn1b[0];
    const float sc = inv[tk] * g;
    #pragma unroll
    for (int i = 0; i < 12; ++i) {
        int d = td * 12 + i;
        vlad[(size_t)n * DESC + (size_t)d * 64 + k] = vloc[i] * sc + b;
    }
}

// ---------------------------------------------------------------------------
// cls_fc split-K (fp32): fpart[ks,n,b] = sum_{k chunk} vlad*W
// ---------------------------------------------------------------------------
__global__ __launch_bounds__(256)
void fsplit_k(const float* __restrict__ vlad, const float* __restrict__ W,
              float* __restrict__ part)
{
    const int bcol0 = (blockIdx.x & 7) * 64;
    const int ks = blockIdx.x >> 3;
    const int kc0 = ks * 256;
    __shared__ float Vs[32][68];
    __shared__ float Ws[32][68];
    const int tid = threadIdx.x, tx = tid & 15, ty = tid >> 4;
    float acc[4][4] = {};

    for (int kc = kc0; kc < kc0 + 256; kc += 32) {
        #pragma unroll
        for (int it = 0; it < 2; ++it) {
            int sl = tid + it * 256;
            int rr = sl >> 3, k4 = (sl & 7) << 2;
            float4 v = *(const float4*)(vlad + (size_t)rr * DESC + kc + k4);
            Vs[k4+0][rr] = v.x; Vs[k4+1][rr] = v.y; Vs[k4+2][rr] = v.z; Vs[k4+3][rr] = v.w;
            float4 w = *(const float4*)(W + (size_t)(bcol0 + rr) * DESC + kc + k4);
            Ws[k4+0][rr] = w.x; Ws[k4+1][rr] = w.y; Ws[k4+2][rr] = w.z; Ws[k4+3][rr] = w.w;
        }
        __syncthreads();
        #pragma unroll
        for (int q = 0; q < 32; ++q) {
            float4 wv = *(const float4*)&Ws[q][tx*4];
            float4 vv = *(const float4*)&Vs[q][ty*4];
            float wa[4] = {wv.x, wv.y, wv.z, wv.w};
            float va[4] = {vv.x, vv.y, vv.z, vv.w};
            #pragma unroll
            for (int i = 0; i < 4; ++i)
                #pragma unroll
                for (int j = 0; j < 4; ++j)
                    acc[i][j] = fmaf(va[i], wa[j], acc[i][j]);
        }
        __syncthreads();
    }
    float* p = part + (size_t)ks * (NN * NB);
    #pragma unroll
    for (int i = 0; i < 4; ++i) {
        int n = ty * 4 + i;
        float4 o = {acc[i][0], acc[i][1], acc[i][2], acc[i][3]};
        *(float4*)(p + (size_t)n * NB + bcol0 + tx*4) = o;
    }
}

__global__ __launch_bounds__(256)
void freduce_k(const float* __restrict__ part, const float* __restrict__ bias,
               const float* __restrict__ bng, const float* __restrict__ bnb,
               float* __restrict__ f)
{
    int idx = blockIdx.x * 256 + threadIdx.x;  // 0..32767
    float s = 0.f;
    for (int ks = 0; ks < 48; ++ks) s += part[(size_t)ks * (NN * NB) + idx];
    int b = idx & (NB - 1);
    f[idx] = (s + bias[b]) * bng[b] + bnb[b];
}

// ---------------------------------------------------------------------------
// cls split-K (x4) with atomicAdd into zeroed d_out.
// ---------------------------------------------------------------------------
__global__ __launch_bounds__(256)
void cls_k(const float* __restrict__ f, const float* __restrict__ W,
           const float* __restrict__ bias, float* __restrict__ out)
{
    const int c0 = (blockIdx.x % 11) * 64;
    const int ks = blockIdx.x / 11;
    __shared__ float Fs[32][68];
    __shared__ float Ws[32][68];
    const int tid = threadIdx.x, tx = tid & 15, ty = tid >> 4;
    float acc[4][4] = {};

    for (int kc = ks * 128; kc < ks * 128 + 128; kc += 32) {
        #pragma unroll
        for (int it = 0; it < 2; ++it) {
            int sl = tid + it * 256;
            int rr = sl >> 3, k4 = (sl & 7) << 2;
            float4 v = *(const float4*)(f + (size_t)rr * NB + kc + k4);
            Fs[k4+0][rr] = v.x; Fs[k4+1][rr] = v.y; Fs[k4+2][rr] = v.z; Fs[k4+3][rr] = v.w;
            int c = c0 + rr;
            float4 w = (c < NCLS) ? *(const float4*)(W + (size_t)c * NB + kc + k4)
                                  : make_float4(0.f, 0.f, 0.f, 0.f);
            Ws[k4+0][rr] = w.x; Ws[k4+1][rr] = w.y; Ws[k4+2][rr] = w.z; Ws[k4+3][rr] = w.w;
        }
        __syncthreads();
        #pragma unroll
        for (int q = 0; q < 32; ++q) {
            float4 wv = *(const float4*)&Ws[q][tx*4];
            float4 fv = *(const float4*)&Fs[q][ty*4];
            float wa[4] = {wv.x, wv.y, wv.z, wv.w};
            float fa[4] = {fv.x, fv.y, fv.z, fv.w};
            #pragma unroll
            for (int i = 0; i < 4; ++i)
                #pragma unroll
                for (int j = 0; j < 4; ++j)
                    acc[i][j] = fmaf(fa[i], wa[j], acc[i][j]);
        }
        __syncthreads();
    }
    #pragma unroll
    for (int i = 0; i < 4; ++i) {
        int n = ty * 4 + i;
        #pragma unroll
        for (int j = 0; j < 4; ++j) {
            int c = c0 + tx * 4 + j;
            if (c < NCLS) {
                float v = acc[i][j] + ((ks == 0) ? bias[c] : 0.f);
                atomicAdd(&out[(size_t)n * NCLS + c], v);
            }
        }
    }
}

// ---------------------------------------------------------------------------
extern "C" void kernel_launch(void* const* d_in, const int* in_sizes, int n_in,
                              void* d_out, int out_size, void* d_ws, size_t ws_size,
                              hipStream_t stream)
{
    const float* features = (const float*)d_in[0];
    const float* fc0_w    = (const float*)d_in[1];
    const float* fc0_b    = (const float*)d_in[2];
    const float* fcgk_w   = (const float*)d_in[3];
    const float* fcgk_b   = (const float*)d_in[4];
    const float* fcg_w    = (const float*)d_in[5];
    const float* fcg_b    = (const float*)d_in[6];
    const float* bn0_g    = (const float*)d_in[7];
    const float* bn0_b    = (const float*)d_in[8];
    const float* cw2      = (const float*)d_in[9];
    const float* bn1_g    = (const float*)d_in[10];
    const float* bn1_b    = (const float*)d_in[11];
    const float* cls_fc_w = (const float*)d_in[12];
    const float* cls_fc_b = (const float*)d_in[13];
    const float* cls_bn_g = (const float*)d_in[14];
    const float* cls_bn_b = (const float*)d_in[15];
    const float* cls_w    = (const float*)d_in[16];
    const float* cls_b    = (const float*)d_in[17];

    // Workspace layout (bytes). Total ~150.6 MB (r5/r7 layout).
    char* ws = (char*)d_ws;
    _Float16* xf16   = (_Float16*)(ws + 0);            // 29,491,200
    _Float16* w1f16  = (_Float16*)(ws + 29491200);     //  2,359,296
    _Float16* w2f16  = (_Float16*)(ws + 31850496);     //  1,572,864
    _Float16* w1t16  = (_Float16*)(ws + 33423360);     //  2,359,296
    _Float16* w2cf16 = (_Float16*)(ws + 35782656);     //    786,432
    float*    biasc  = (float*)   (ws + 36569088);     //      4,096
    float*    wgc    = (float*)   (ws + 36573184);     //     24,576
    _Float16* xdot16 = (_Float16*)(ws + 36597760);     // 58,982,400
    _Float16* act16  = (_Float16*)(ws + 95580160);     // 19,660,800
    float*    sigma  = (float*)   (ws + 115240960);    //    614,400
    float*    apart  = (float*)   (ws + 115855360);    //    131,072
    float*    vpart  = (float*)   (ws + 115986432);    // 25,165,824
    float*    vlad   = (float*)   (ws + 141152256);    //  3,145,728
    float*    fpart  = (float*)   (ws + 144297984);    //  6,291,456 -> 150,589,440

    float* cls_out = (float*)d_out;          // 64*701 (atomically accumulated)
    float* f_out   = cls_out + NN * NCLS;    // 64*512

    dim3 blk(256);

    hipMemsetAsync(wgc, 0, GG * CC * sizeof(float), stream);
    hipMemsetAsync(cls_out, 0, (size_t)NN * NCLS * sizeof(float), stream);

    // 1. fused setup: packs + transpose + composed biases + Wgc
    setup_k<<<17224, blk, 0, stream>>>(features, fc0_w, fcgk_w, fcg_w,
                                       fc0_b, fcgk_b, fcg_b,
                                       xf16, w1f16, w2f16, w1t16, biasc, wgc);

    // 2. W2c[f,c] = W2@W1  (512x768, K=1536) -> fp16
    hgemm_nt<true, false, false, false><<<24, blk, 0, stream>>>(
        w2f16, w1t16, nullptr, nullptr, nullptr, nullptr, w2cf16, CC, EE, 6);

    // 3. x_dot = x @ W1^T + b0 (19200x1536, K=768) -> fp16 (vlad only)
    hgemm_nt<true, false, false, true><<<1800, blk, 0, stream>>>(
        xf16, w1f16, fc0_b, nullptr, nullptr, nullptr, xdot16, EE, CC, 12);

    // 4. alpha_g = sigmoid(x @ Wgc^T + bgc)
    alpha_sig_k<<<1200, blk, 0, stream>>>(xf16, wgc, biasc + FF, sigma);

    // 5. act = softmax((x @ W2c^T + biasc)*bn0) * gate (19200x512, K=768) -> fp16
    hgemm_nt<true, true, true, true><<<600, blk, 0, stream>>>(
        xf16, w2cf16, biasc, bn0_g, bn0_b, sigma, act16, FF, CC, 4);

    // 6. vlad partials (split-P x8, VALU) + asum partials, one launch
    vladact_k<<<2048, blk, 0, stream>>>(act16, xdot16, vpart, apart);

    // 7. reduce + (-a*cw2) + L1-norm + bn1 -> vlad (fp32)
    vladnorm_k<<<256, blk, 0, stream>>>(vpart, apart, cw2, bn1_g, bn1_b, vlad);

    // 8. f = vlad @ cls_fc_w^T (+bias)*bn   (fp32 split-K 48)
    fsplit_k<<<384, blk, 0, stream>>>(vlad, cls_fc_w, fpart);
    freduce_k<<<128, blk, 0, stream>>>(fpart, cls_fc_b, cls_bn_g, cls_bn_b, f_out);

    // 9. cls = f @ cls_w^T + cls_b  (split-K x4, atomic into zeroed out)
    cls_k<<<44, blk, 0, stream>>>(f_out, cls_w, cls_b, cls_out);
}